// Round 19
// baseline (254.414 us; speedup 1.0000x reference)
//
#include <hip/hip_runtime.h>
#include <stdint.h>

typedef int v4i  __attribute__((ext_vector_type(4)));
typedef int v16i __attribute__((ext_vector_type(16)));

// ---------------------------------------------------------------------------
// Fused quantize kernel (r16-r18 verified): blocks [0,M) quantize x rows;
// blocks [M,M+N) pack w rows; one launch, paths run concurrently.
// ---------------------------------------------------------------------------
__global__ void quant_fused_kernel(const float* __restrict__ x,
                                   const int* __restrict__ w,
                                   int8_t* __restrict__ xq,
                                   int8_t* __restrict__ wq,
                                   int* __restrict__ sum_x,
                                   int* __restrict__ sum_w,
                                   const float* __restrict__ p_scale,
                                   const int* __restrict__ p_zp,
                                   int M, int K) {
    const int t = threadIdx.x;
    const int nchunk = K >> 10;
    int lsum = 0;
    if (blockIdx.x < M) {
        const int row = blockIdx.x;
        const float s = p_scale[0];
        const float zpf = (float)p_zp[0];
        const float* xr = x + (size_t)row * K;
        int8_t* qr = xq + (size_t)row * K;
        for (int i = 0; i < nchunk; ++i) {
            const int idx = (i << 10) + (t << 2);
            const float4 v = *reinterpret_cast<const float4*>(xr + idx);
            const float f0 = fminf(fmaxf(rintf(v.x / s) + zpf, -128.f), 127.f);
            const float f1 = fminf(fmaxf(rintf(v.y / s) + zpf, -128.f), 127.f);
            const float f2 = fminf(fmaxf(rintf(v.z / s) + zpf, -128.f), 127.f);
            const float f3 = fminf(fmaxf(rintf(v.w / s) + zpf, -128.f), 127.f);
            const int i0 = (int)f0, i1 = (int)f1, i2 = (int)f2, i3 = (int)f3;
            lsum += i0 + i1 + i2 + i3;
            const unsigned pk = (unsigned)(i0 & 255) | ((unsigned)(i1 & 255) << 8) |
                                ((unsigned)(i2 & 255) << 16) | ((unsigned)(i3 & 255) << 24);
            *reinterpret_cast<unsigned*>(qr + idx) = pk;
        }
    } else {
        const int row = blockIdx.x - M;
        const int* wr_ = w + (size_t)row * K;
        int8_t* qr = wq + (size_t)row * K;
        for (int i = 0; i < nchunk; ++i) {
            const int idx = (i << 10) + (t << 2);
            const int4 v = *reinterpret_cast<const int4*>(wr_ + idx);
            lsum += v.x + v.y + v.z + v.w;
            const unsigned pk = (unsigned)(v.x & 255) | ((unsigned)(v.y & 255) << 8) |
                                ((unsigned)(v.z & 255) << 16) | ((unsigned)(v.w & 255) << 24);
            *reinterpret_cast<unsigned*>(qr + idx) = pk;
        }
    }
    __shared__ int wsum[4];
    #pragma unroll
    for (int off = 32; off > 0; off >>= 1) lsum += __shfl_down(lsum, off);
    if ((t & 63) == 0) wsum[t >> 6] = lsum;
    __syncthreads();
    if (t == 0) {
        const int tot = wsum[0] + wsum[1] + wsum[2] + wsum[3];
        if (blockIdx.x < M) sum_x[blockIdx.x] = tot;
        else                sum_w[blockIdx.x - M] = tot;
    }
}

// ---------------------------------------------------------------------------
// GEMM: ZERO-BARRIER free-running waves (the last untested structural cell).
// 256x256 tile, 4 waves (2x2), wave-tile 128x128 -- r10's verified fragment
// math -- but staging is WAVE-PRIVATE: each wave DMAs its own 128 A-rows +
// 128 B-rows into a private LDS region. No wave reads another wave's LDS =>
// NO barrier anywhere in the K-loop. Each wave free-runs; the CU scheduler
// overlaps waves' stalls (m114: time ~ max, not sum).
//
// Why: the r4-r18 falsification matrix (all ~28.3 cyc/MFMA) eliminated LDS
// BW, conflicts, barrier COUNT, occupancy, staging mechanism, phase shape,
// and HBM supply. The shared residual property is barrier CONVERGENCE:
// every tile costs max-over-waves of latency chains. This kernel removes
// convergence entirely. Cost: A/B halves staged by 2 waves each (2x DMA,
// L2-absorbed; r18's XCD-stripe decode keeps A in the XCD's own L2).
//
// Race proof -- wave-local reasoning ONLY (no cross-wave hazards exist):
//  (1) DMA(t+1) targets slot (t+1)&1; reads of tile t use slot t&1. Disjoint.
//  (2) WAR on slot reuse: tile t-1's ds_reads completed (lgkmcnt before its
//      MFMAs, which precede in program order) before tile t+1's DMA issues;
//      the DMA's LDS write lands later still. Safe.
//  (3) Per-wave DMA stream is pure (only gload_lds counts vmcnt); the
//      tile-end vmcnt(0) (r9-verified semantics) retires the private
//      staging before the next tile reads it. "memory"-clobber asm orders
//      the following ds_reads.
//
// Layout per wave: [2 slots][128 rows][4 chunks'] with the r6-verified
// swizzle chunk' = chunk ^ f(row), f(row)=((row>>1)^(row>>3))&3.
// DMA j (j=0..7 per operand): lane l -> local row r=j*16+(l>>2), stored
// chunk' l&3, source chunk (l&3)^f(r); dest chunk index j*64+l (linear,
// wave-uniform base). Reads: r10's verified formulas on the private region.
// ---------------------------------------------------------------------------
#define BM 256
#define BN 256
#define BKB 64

__device__ __forceinline__ void gload_lds16(const void* g, void* l) {
    __builtin_amdgcn_global_load_lds(
        (const __attribute__((address_space(1))) unsigned int*)g,
        (__attribute__((address_space(3))) unsigned int*)l, 16, 0, 0);
}

#define MFMA_I8 __builtin_amdgcn_mfma_i32_32x32x32_i8

__global__ __launch_bounds__(256, 1)
void gemm_i8_kernel(const int8_t* __restrict__ xq,
                    const int8_t* __restrict__ wq,
                    const int* __restrict__ sum_x,
                    const int* __restrict__ sum_w,
                    const float* __restrict__ bias,
                    float* __restrict__ out,
                    const float* __restrict__ p_sa,
                    const int* __restrict__ p_zpa,
                    const float* __restrict__ p_sw,
                    const int* __restrict__ p_wzp,
                    int M, int N, int K) {
    __shared__ v4i ldsAp[4][2][512];    // [wave][slot][chunk16B] = 64 KiB
    __shared__ v4i ldsBp[4][2][512];    // 128 KiB total

    const int tid = threadIdx.x;        // 256 threads = 4 waves
    const int lane = tid & 63;
    const int wid = tid >> 6;
    const int wr = wid >> 1;            // 0..1: rows wr*128..+127
    const int wc = wid & 1;             // 0..1: cols wc*128..+127

    // XCD-L2-resident decode (r18-verified: FETCH 271->148MB): XCD owns an
    // M-stripe of nwgy/8 m-tiles (4MB of A = one XCD-L2), sweeps n fastest.
    const int nwgy = M / BM;            // 32
    const int nwgx = N / BN;            // 16
    const int spx = nwgy >> 3;          // 4
    const int bid = blockIdx.x;
    const int xcd = bid & 7;
    const int loc = bid >> 3;
    const int m0 = (xcd * spx + loc / nwgx) * BM;
    const int n0 = (loc % nwgx) * BN;

    // ---- wave-private staging: bases + per-lane per-j source offsets.
    const int8_t* aW = xq + (size_t)(m0 + wr * 128) * K;
    const int8_t* bW = wq + (size_t)(n0 + wc * 128) * K;
    int off[8];                         // static-indexed (rule 20) -> VGPRs
    #pragma unroll
    for (int j = 0; j < 8; ++j) {
        const int r = j * 16 + (lane >> 2);                 // local row
        const int sc = (lane & 3) ^ (((r >> 1) ^ (r >> 3)) & 3);
        off[j] = r * K + sc * 16;
    }

    // ---- fragment reads on the private region (r10-verified formulas):
    // local row = i*32 + (lane&31); logical chunk c = ks*2 + (lane>>5);
    // stored at c ^ f(row), f = ((lane>>1)^(lane>>3))&3 (row base %32==0).
    const int sel = ((lane >> 1) ^ (lane >> 3)) & 3;
    const int hi = lane >> 5;
    const int c0 = hi ^ sel;
    const int c1 = (2 + hi) ^ sel;
    int frow[4];
    #pragma unroll
    for (int i = 0; i < 4; ++i) frow[i] = (i * 32 + (lane & 31)) * 4;

    v16i acc[4][4] = {};
    const int NT = K / BKB;             // 64

#define STAGE(SLOT, T_) do {                                                  \
        const int kof_ = (T_) * BKB;                                          \
        _Pragma("unroll")                                                     \
        for (int j = 0; j < 8; ++j) {                                         \
            gload_lds16(aW + kof_ + off[j], &ldsAp[wid][SLOT][j * 64]);       \
            gload_lds16(bW + kof_ + off[j], &ldsBp[wid][SLOT][j * 64]);       \
        }                                                                     \
    } while (0)

    // ---- prologue: stage tile 0 privately; wait own DMA. NO barrier.
    STAGE(0, 0);
    asm volatile("s_waitcnt vmcnt(0)" ::: "memory");
    __builtin_amdgcn_sched_barrier(0);

    for (int t = 0; t < NT; ++t) {
        // issue next tile's private staging first (latency hides under
        // this tile's reads + MFMAs; ~1300 cyc of wave-local work)
        if (t + 1 < NT) STAGE((t + 1) & 1, t + 1);
        const v4i* LA = ldsAp[wid][t & 1];
        const v4i* LB = ldsBp[wid][t & 1];
        v4i a[4][2], b[4][2];
        #pragma unroll
        for (int i = 0; i < 4; ++i) {
            a[i][0] = LA[frow[i] + c0];
            a[i][1] = LA[frow[i] + c1];
        }
        #pragma unroll
        for (int i = 0; i < 4; ++i) {
            b[i][0] = LB[frow[i] + c0];
            b[i][1] = LB[frow[i] + c1];
        }
        __builtin_amdgcn_s_setprio(1);
        #pragma unroll
        for (int ks = 0; ks < 2; ++ks)
            #pragma unroll
            for (int rf = 0; rf < 4; ++rf)
                #pragma unroll
                for (int cf = 0; cf < 4; ++cf)
                    acc[rf][cf] = MFMA_I8(a[rf][ks], b[cf][ks], acc[rf][cf], 0, 0, 0);
        __builtin_amdgcn_s_setprio(0);
        // retire own private staging before the next tile reads it.
        if (t + 1 < NT) {
            asm volatile("s_waitcnt vmcnt(0)" ::: "memory");
            __builtin_amdgcn_sched_barrier(0);
        }
    }
#undef STAGE

    // ---- epilogue (r10-verified): y = (acc - wzp*sx - zp*sw + K*zp*wzp)*s + b
    const float stot = p_sa[0] * p_sw[0];
    const int zpa = p_zpa[0];
    const int wzp = p_wzp[0];
    const int kzz = K * zpa * wzp;
    const int coll = lane & 31;
    const int rhi = (lane >> 5) * 4;

    #pragma unroll
    for (int cf = 0; cf < 4; ++cf) {
        const int cg = n0 + wc * 128 + cf * 32 + coll;
        const int sw = sum_w[cg];
        const float bb = bias[cg];
        #pragma unroll
        for (int rf = 0; rf < 4; ++rf) {
            const int rbase = m0 + wr * 128 + rf * 32 + rhi;
            #pragma unroll
            for (int r = 0; r < 16; ++r) {
                const int rowg = rbase + (r & 3) + 8 * (r >> 2);
                const int iv = acc[rf][cf][r] - wzp * sum_x[rowg] - zpa * sw + kzz;
                out[(size_t)rowg * N + cg] = (float)iv * stot + bb;
            }
        }
    }
}

// ---------------------------------------------------------------------------
extern "C" void kernel_launch(void* const* d_in, const int* in_sizes, int n_in,
                              void* d_out, int out_size, void* d_ws, size_t ws_size,
                              hipStream_t stream) {
    const float* x     = (const float*)d_in[0];
    const int*   w     = (const int*)d_in[1];
    const float* bias  = (const float*)d_in[2];
    const float* p_sa  = (const float*)d_in[3];
    const int*   p_zpa = (const int*)d_in[4];
    const float* p_sw  = (const float*)d_in[5];
    const int*   p_wzp = (const int*)d_in[6];

    const int N = in_sizes[2];             // OUT
    const int K = in_sizes[1] / N;         // IN
    const int M = in_sizes[0] / K;         // B*S

    int8_t* xq = (int8_t*)d_ws;
    int8_t* wq = xq + (size_t)M * K;
    int* sum_x = (int*)(wq + (size_t)N * K);
    int* sum_w = sum_x + M;

    quant_fused_kernel<<<M + N, 256, 0, stream>>>(x, w, xq, wq, sum_x, sum_w,
                                                  p_sa, p_zpa, M, K);

    const int nwg = (M / BM) * (N / BN);   // 512
    gemm_i8_kernel<<<nwg, 256, 0, stream>>>(xq, wq, sum_x, sum_w, bias,
                                            (float*)d_out, p_sa, p_zpa, p_sw, p_wzp,
                                            M, N, K);
}

// Round 20
// 229.412 us; speedup vs baseline: 1.1090x; 1.1090x over previous
//
#include <hip/hip_runtime.h>
#include <stdint.h>

typedef int v4i  __attribute__((ext_vector_type(4)));
typedef int v16i __attribute__((ext_vector_type(16)));

// ---------------------------------------------------------------------------
// Fused quantize kernel (r16-r18 verified): blocks [0,M) quantize x rows;
// blocks [M,M+N) pack w rows; one launch, paths run concurrently.
// AT MEMORY ROOFLINE: 250MB floor traffic ~= 40us at 6.3TB/s achievable.
// ---------------------------------------------------------------------------
__global__ void quant_fused_kernel(const float* __restrict__ x,
                                   const int* __restrict__ w,
                                   int8_t* __restrict__ xq,
                                   int8_t* __restrict__ wq,
                                   int* __restrict__ sum_x,
                                   int* __restrict__ sum_w,
                                   const float* __restrict__ p_scale,
                                   const int* __restrict__ p_zp,
                                   int M, int K) {
    const int t = threadIdx.x;
    const int nchunk = K >> 10;
    int lsum = 0;
    if (blockIdx.x < M) {
        const int row = blockIdx.x;
        const float s = p_scale[0];
        const float zpf = (float)p_zp[0];
        const float* xr = x + (size_t)row * K;
        int8_t* qr = xq + (size_t)row * K;
        for (int i = 0; i < nchunk; ++i) {
            const int idx = (i << 10) + (t << 2);
            const float4 v = *reinterpret_cast<const float4*>(xr + idx);
            const float f0 = fminf(fmaxf(rintf(v.x / s) + zpf, -128.f), 127.f);
            const float f1 = fminf(fmaxf(rintf(v.y / s) + zpf, -128.f), 127.f);
            const float f2 = fminf(fmaxf(rintf(v.z / s) + zpf, -128.f), 127.f);
            const float f3 = fminf(fmaxf(rintf(v.w / s) + zpf, -128.f), 127.f);
            const int i0 = (int)f0, i1 = (int)f1, i2 = (int)f2, i3 = (int)f3;
            lsum += i0 + i1 + i2 + i3;
            const unsigned pk = (unsigned)(i0 & 255) | ((unsigned)(i1 & 255) << 8) |
                                ((unsigned)(i2 & 255) << 16) | ((unsigned)(i3 & 255) << 24);
            *reinterpret_cast<unsigned*>(qr + idx) = pk;
        }
    } else {
        const int row = blockIdx.x - M;
        const int* wr_ = w + (size_t)row * K;
        int8_t* qr = wq + (size_t)row * K;
        for (int i = 0; i < nchunk; ++i) {
            const int idx = (i << 10) + (t << 2);
            const int4 v = *reinterpret_cast<const int4*>(wr_ + idx);
            lsum += v.x + v.y + v.z + v.w;
            const unsigned pk = (unsigned)(v.x & 255) | ((unsigned)(v.y & 255) << 8) |
                                ((unsigned)(v.z & 255) << 16) | ((unsigned)(v.w & 255) << 24);
            *reinterpret_cast<unsigned*>(qr + idx) = pk;
        }
    }
    __shared__ int wsum[4];
    #pragma unroll
    for (int off = 32; off > 0; off >>= 1) lsum += __shfl_down(lsum, off);
    if ((t & 63) == 0) wsum[t >> 6] = lsum;
    __syncthreads();
    if (t == 0) {
        const int tot = wsum[0] + wsum[1] + wsum[2] + wsum[3];
        if (blockIdx.x < M) sum_x[blockIdx.x] = tot;
        else                sum_w[blockIdx.x - M] = tot;
    }
}

// ---------------------------------------------------------------------------
// GEMM (r18-verified best, 188.5us = 1458 TOPS): 256x256 tile, 4 waves 2x2,
// wave-tile 128x128, pure-DMA 4-slot pipeline, distance-2 prefetch, one
// barrier + one counted vmcnt(8) per K-tile, XCD-L2-resident block order.
//
// Plateau characterization (r4-r19 full falsification matrix, all >=188us /
// ~28.3 cyc/MFMA vs 9.15 floor): eliminated = LDS BW (r10), bank conflicts
// (r11: zeroed, no change), barrier count (r10), barrier existence (r19:
// wave-private LDS, zero barriers -- worse), occupancy (r14: 2 blocks/CU,
// no change), staging mechanism (r16 reg-staged / r13 A-direct / r9
// B-direct -- all worse), phase granularity (r11), segment length (r15),
// HBM over-fetch (r18: FETCH 271->148MB, -5us). Residual: per-tile
// L2->DMA->LDS supply chain latency under lockstep; not addressable within
// this structure family at HIP source level.
//
// XCD-L2-resident decode (r18: FETCH 271->148MB): each XCD owns an M-stripe
// of nwgy/8 = 4 m-tiles (4MB of A = one XCD-L2), sweeps n fastest.
// Slot safety: tile t staged at t-2; per-wave vmcnt(8) at end of t-1
// retires t's staging (pure in-order DMA stream, r9-verified semantics);
// barrier publishes. WAR: slot (t+2)&3 overwritten at t, last read t-2.
// Swizzle (r6-verified): stored chunk' = chunk ^ f(row),
// f(row)=((row>>1)^(row>>3))&3; linear DMA dest, inverse-swizzled source.
// ---------------------------------------------------------------------------
#define BM 256
#define BN 256
#define BKB 64
#define NSLOT 4

__device__ __forceinline__ void gload_lds16(const void* g, void* l) {
    __builtin_amdgcn_global_load_lds(
        (const __attribute__((address_space(1))) unsigned int*)g,
        (__attribute__((address_space(3))) unsigned int*)l, 16, 0, 0);
}

#define MFMA_I8 __builtin_amdgcn_mfma_i32_32x32x32_i8

__global__ __launch_bounds__(256, 1)
void gemm_i8_kernel(const int8_t* __restrict__ xq,
                    const int8_t* __restrict__ wq,
                    const int* __restrict__ sum_x,
                    const int* __restrict__ sum_w,
                    const float* __restrict__ bias,
                    float* __restrict__ out,
                    const float* __restrict__ p_sa,
                    const int* __restrict__ p_zpa,
                    const float* __restrict__ p_sw,
                    const int* __restrict__ p_wzp,
                    int M, int N, int K) {
    __shared__ v4i ldsA[NSLOT][1024];   // 4 slots * 16KB = 64 KiB
    __shared__ v4i ldsB[NSLOT][1024];   // 128 KiB total

    const int tid = threadIdx.x;        // 256 threads = 4 waves
    const int lane = tid & 63;
    const int wid = tid >> 6;
    const int wr = wid >> 1;            // 0..1: rows wr*128..+127
    const int wc = wid & 1;             // 0..1: cols wc*128..+127

    // XCD-L2-resident decode: XCD owns an M-stripe, sweeps n fastest.
    const int nwgy = M / BM;            // 32
    const int nwgx = N / BN;            // 16
    const int spx = nwgy >> 3;          // m-tiles per XCD stripe (4)
    const int bid = blockIdx.x;
    const int xcd = bid & 7;
    const int loc = bid >> 3;           // 0 .. spx*nwgx-1
    const int m0 = (xcd * spx + loc / nwgx) * BM;
    const int n0 = (loc % nwgx) * BN;

    // ---- staging: thread tid handles chunks {tid + k*256, k=0..3} per
    // operand per tile. chunk p: row = p>>2, stored chunk' = p&3.
    const int srow = tid >> 2;
    const int schunk = (tid & 3) ^ (((srow >> 1) ^ (srow >> 3)) & 3);
    const int8_t* aS = xq + (size_t)(m0 + srow) * K + schunk * 16;
    const int8_t* bS = wq + (size_t)(n0 + srow) * K + schunk * 16;
    const size_t qtr = (size_t)64 * K;                  // +64 rows
    const int dbase = wid * 64;                         // wave-uniform

    // ---- fragment reads: row = (wr|wc)*128 + f_idx*32 + (lane&31),
    // logical chunk c = ks*2 + (lane>>5); stored at c ^ f(row).
    const int sel = ((lane >> 1) ^ (lane >> 3)) & 3;
    const int hi = lane >> 5;
    const int c0 = hi ^ sel;            // ks0 stored chunk
    const int c1 = (2 + hi) ^ sel;      // ks1 stored chunk
    int arow[4], brow[4];
    #pragma unroll
    for (int i = 0; i < 4; ++i) {
        arow[i] = (wr * 128 + i * 32 + (lane & 31)) * 4;
        brow[i] = (wc * 128 + i * 32 + (lane & 31)) * 4;
    }

    v16i acc[4][4] = {};
    const int NT = K / BKB;             // 64

#define STAGE(SLOT, T_) do {                                                  \
        const int8_t* pa_ = aS + (size_t)(T_) * BKB;                          \
        const int8_t* pb_ = bS + (size_t)(T_) * BKB;                          \
        _Pragma("unroll")                                                     \
        for (int k_ = 0; k_ < 4; ++k_) {                                      \
            gload_lds16(pa_ + k_ * qtr, &ldsA[SLOT][k_ * 256 + dbase]);       \
            gload_lds16(pb_ + k_ * qtr, &ldsB[SLOT][k_ * 256 + dbase]);       \
        }                                                                     \
    } while (0)

    // ---- prologue: stage tiles 0 and 1 (8 DMA each)
    STAGE(0, 0);
    STAGE(1, 1);
    asm volatile("s_waitcnt vmcnt(8)" ::: "memory");   // tile 0 landed
    __builtin_amdgcn_sched_barrier(0);
    __builtin_amdgcn_s_barrier();

    for (int t = 0; t < NT; ++t) {
        const v4i* LA = ldsA[t & 3];
        const v4i* LB = ldsB[t & 3];
        v4i a[4][2], b[4][2];
        #pragma unroll
        for (int i = 0; i < 4; ++i) {
            a[i][0] = LA[arow[i] + c0];
            a[i][1] = LA[arow[i] + c1];
        }
        #pragma unroll
        for (int i = 0; i < 4; ++i) {
            b[i][0] = LB[brow[i] + c0];
            b[i][1] = LB[brow[i] + c1];
        }
        if (t + 2 < NT) STAGE((t + 2) & 3, t + 2);
        __builtin_amdgcn_s_setprio(1);
        #pragma unroll
        for (int ks = 0; ks < 2; ++ks)
            #pragma unroll
            for (int rf = 0; rf < 4; ++rf)
                #pragma unroll
                for (int cf = 0; cf < 4; ++cf)
                    acc[rf][cf] = MFMA_I8(a[rf][ks], b[cf][ks], acc[rf][cf], 0, 0, 0);
        __builtin_amdgcn_s_setprio(0);
        // counted wait on the PURE DMA stream: this tile issued 8 (t+2);
        // waiting to 8 retires tile t+1's stages (in-order; verified
        // r3-r6/r10/r17/r18).
        if (t + 2 < NT) {
            asm volatile("s_waitcnt vmcnt(8)" ::: "memory");
        } else if (t + 1 < NT) {
            asm volatile("s_waitcnt vmcnt(0)" ::: "memory");
        }
        __builtin_amdgcn_sched_barrier(0);
        __builtin_amdgcn_s_barrier();
    }
#undef STAGE

    // ---- epilogue: y = (acc - wzp*sum_x[m] - zp*sum_w[n] + K*zp*wzp)*(sa*sw) + bias[n]
    const float stot = p_sa[0] * p_sw[0];
    const int zpa = p_zpa[0];
    const int wzp = p_wzp[0];
    const int kzz = K * zpa * wzp;
    const int coll = lane & 31;
    const int rhi = (lane >> 5) * 4;

    #pragma unroll
    for (int cf = 0; cf < 4; ++cf) {
        const int cg = n0 + wc * 128 + cf * 32 + coll;
        const int sw = sum_w[cg];
        const float bb = bias[cg];
        #pragma unroll
        for (int rf = 0; rf < 4; ++rf) {
            const int rbase = m0 + wr * 128 + rf * 32 + rhi;
            #pragma unroll
            for (int r = 0; r < 16; ++r) {
                const int rowg = rbase + (r & 3) + 8 * (r >> 2);
                const int iv = acc[rf][cf][r] - wzp * sum_x[rowg] - zpa * sw + kzz;
                out[(size_t)rowg * N + cg] = (float)iv * stot + bb;
            }
        }
    }
}

// ---------------------------------------------------------------------------
extern "C" void kernel_launch(void* const* d_in, const int* in_sizes, int n_in,
                              void* d_out, int out_size, void* d_ws, size_t ws_size,
                              hipStream_t stream) {
    const float* x     = (const float*)d_in[0];
    const int*   w     = (const int*)d_in[1];
    const float* bias  = (const float*)d_in[2];
    const float* p_sa  = (const float*)d_in[3];
    const int*   p_zpa = (const int*)d_in[4];
    const float* p_sw  = (const float*)d_in[5];
    const int*   p_wzp = (const int*)d_in[6];

    const int N = in_sizes[2];             // OUT
    const int K = in_sizes[1] / N;         // IN
    const int M = in_sizes[0] / K;         // B*S

    int8_t* xq = (int8_t*)d_ws;
    int8_t* wq = xq + (size_t)M * K;
    int* sum_x = (int*)(wq + (size_t)N * K);
    int* sum_w = sum_x + M;

    quant_fused_kernel<<<M + N, 256, 0, stream>>>(x, w, xq, wq, sum_x, sum_w,
                                                  p_sa, p_zpa, M, K);

    const int nwg = (M / BM) * (N / BN);   // 512
    gemm_i8_kernel<<<nwg, 256, 0, stream>>>(xq, wq, sum_x, sum_w, bias,
                                            (float*)d_out, p_sa, p_zpa, p_sw, p_wzp,
                                            M, N, K);
}